// Round 10
// baseline (137.369 us; speedup 1.0000x reference)
//
#include <hip/hip_runtime.h>
#include <hip/hip_bf16.h>
#include <stdint.h>

// MahalanobisEnsembleLoss: out = sum_l w[l] * mean_n( v^T M_l v ),  v = F[l,n,:] - MEAN[l,idx[n],:]
// Decomposition (asymmetry-correct, R8-validated):  SY = fp16(0.5*(M + M^T))
//   q_n = f^T SY f  -  f . GH[idx_n]  +  SS[idx_n]
//   GH[c] = 2*(SY . mean[c]) (fp16),  SS[c] = mean[c]^T SY mean[c] (fp32)
// R10: main GEMM W = Fh*SY^T ported to the m97-shape (measured 874-912 TF on gfx950):
// BM=128 x BN=128 strip, BK=32, 4 waves, A reg-staged fp32->fp16, B via global_load_lds
// (pre-swizzled source), dbuf LDS w/ add-rotate granule swizzle, 3 blocks/CU.
#define LDIM 4
#define NDIM 16384
#define DDIM 512
#define CDIM 1000
#define NSTEP 16

// ---- workspace layout (bytes) ----
#define SY_ELEMS ((size_t)LDIM * DDIM * DDIM)
#define GH_OFF   (SY_ELEMS * 2)
#define GH_ELEMS ((size_t)LDIM * CDIM * DDIM)
#define SS_OFF   (GH_OFF + GH_ELEMS * 2)
#define SS_FLOATS ((size_t)LDIM * 1024)
#define WS_NEED  (SS_OFF + SS_FLOATS * 4)   // ~6.11 MiB (R1 proved >=6.29 MiB available)

typedef __attribute__((ext_vector_type(8))) _Float16 f16x8;
typedef __attribute__((ext_vector_type(4))) float f32x4;

__device__ __forceinline__ unsigned short f2h(float x) {
  union { _Float16 h; unsigned short u; } c; c.h = (_Float16)x; return c.u;
}
__device__ __forceinline__ float h2f(unsigned short u) {
  union { unsigned short u; _Float16 h; } c; c.u = u; return (float)c.h;
}
__device__ __forceinline__ f16x8 cvt8(float4 a, float4 b) {
  f16x8 p;
  p[0] = (_Float16)a.x; p[1] = (_Float16)a.y; p[2] = (_Float16)a.z; p[3] = (_Float16)a.w;
  p[4] = (_Float16)b.x; p[5] = (_Float16)b.y; p[6] = (_Float16)b.z; p[7] = (_Float16)b.w;
  return p;
}
__device__ __forceinline__ void gload16(const void* g, void* l) {
  __builtin_amdgcn_global_load_lds(
      (const __attribute__((address_space(1))) void*)g,
      (__attribute__((address_space(3))) void*)l, 16, 0, 0);
}

// ---- main-kernel LDS: A dbuf 2x8KB | B dbuf 2x8KB | ids[128] | sval[128] | red[4]
// Tile layout [128 rows][32 e] fp16 = 64 B/row, 4 granules of 16 B.
// Swizzle: phys_granule = (logical_g + ((row>>1)&3)) & 3  -> 2 lanes/bank (free).
#define AB0 0
#define BB0 16384
#define IDS_OFF 32768
#define SVAL_OFF 33280
#define RED_OFF 33792
#define LDS_MAIN 33808
#define LDS_PREP 65536

// K0: SY = fp16(0.5*(M + M^T)). Coalesced row read + strided transposed read.
extern "C" __global__ void mel_mconv(const float* __restrict__ IC,
                                     unsigned short* __restrict__ SY) {
  size_t i4 = (size_t)blockIdx.x * 256 + threadIdx.x;  // covers L*D*D/4
  size_t base = i4 * 4;
  int l = (int)(base >> 18);
  int rem = (int)(base & 262143);
  int e = rem & 511;
  int d = rem >> 9;
  float4 v = *(const float4*)(IC + base);
  const float* icl = IC + ((size_t)l << 18);
  float t0 = icl[(size_t)(e + 0) * DDIM + d];
  float t1 = icl[(size_t)(e + 1) * DDIM + d];
  float t2 = icl[(size_t)(e + 2) * DDIM + d];
  float t3 = icl[(size_t)(e + 3) * DDIM + d];
  *(ushort4*)(SY + base) = make_ushort4(f2h(0.5f * (v.x + t0)), f2h(0.5f * (v.y + t1)),
                                        f2h(0.5f * (v.z + t2)), f2h(0.5f * (v.w + t3)));
}

// K1: P = meanh . SYh^T ; GH[c,:] = fp16(2P), SS[c] = sum_d meanh*P. 64 blocks x 512 thr.
extern "C" __global__ __launch_bounds__(512, 2)
void mel_prep(const float* __restrict__ MEAN, const unsigned short* __restrict__ SY,
              unsigned short* __restrict__ GH, float* __restrict__ SS) {
  extern __shared__ __align__(16) char lds[];
  const int t = threadIdx.x, lane = t & 63, w = t >> 6;
  const int l = blockIdx.x & 3, ct = blockIdx.x >> 2;
  const int row0 = ct * 64;
  const int col0 = w * 64, lrow = lane & 15, lkg = lane >> 4;
  const int lke = lkg << 3;

  {  // stage 64 mean rows as fp16 (rows >= CDIM -> 0); [64][512] XOR-granule layout
    const int srow = t >> 3;
    const int grow = row0 + srow;
    const float* mr = MEAN + ((size_t)l * CDIM + grow) * DDIM + ((t & 7) << 3);
    const int swb = srow * 1024 + (((t & 7) ^ (srow & 7)) << 4);
    const float4 z4 = {0.f, 0.f, 0.f, 0.f};
    for (int c = 0; c < 8; ++c) {
      float4 x = z4, y = z4;
      if (grow < CDIM) { x = *(const float4*)(mr + c * 64); y = *(const float4*)(mr + c * 64 + 4); }
      *(f16x8*)(lds + swb + c * 128) = cvt8(x, y);
    }
  }
  __syncthreads();

  const unsigned short* bw = SY + (size_t)l * DDIM * DDIM + (size_t)(col0 + lrow) * DDIM + lke;
  f32x4 acc[4][4];
#pragma unroll
  for (int i = 0; i < 4; ++i)
#pragma unroll
    for (int j = 0; j < 4; ++j) acc[i][j] = {0.f, 0.f, 0.f, 0.f};

  for (int c = 0; c < 8; ++c) {
#pragma unroll
    for (int ks = 0; ks < 2; ++ks) {
      const unsigned short* bc = bw + c * 64 + ks * 32;
      f16x8 b0 = *(const f16x8*)(bc);
      f16x8 b1 = *(const f16x8*)(bc + 16 * DDIM);
      f16x8 b2 = *(const f16x8*)(bc + 32 * DDIM);
      f16x8 b3 = *(const f16x8*)(bc + 48 * DDIM);
      const int xo = c * 128 + ((((ks << 2) + lkg) ^ (lrow & 7)) << 4);
      f16x8 a0 = *(const f16x8*)(lds + lrow * 1024 + xo);
      f16x8 a1 = *(const f16x8*)(lds + (16 + lrow) * 1024 + xo);
      f16x8 a2 = *(const f16x8*)(lds + (32 + lrow) * 1024 + xo);
      f16x8 a3 = *(const f16x8*)(lds + (48 + lrow) * 1024 + xo);
#pragma unroll
      for (int nf = 0; nf < 4; ++nf) {
        f16x8 a = nf == 0 ? a0 : nf == 1 ? a1 : nf == 2 ? a2 : a3;
        acc[nf][0] = __builtin_amdgcn_mfma_f32_16x16x32_f16(a, b0, acc[nf][0], 0, 0, 0);
        acc[nf][1] = __builtin_amdgcn_mfma_f32_16x16x32_f16(a, b1, acc[nf][1], 0, 0, 0);
        acc[nf][2] = __builtin_amdgcn_mfma_f32_16x16x32_f16(a, b2, acc[nf][2], 0, 0, 0);
        acc[nf][3] = __builtin_amdgcn_mfma_f32_16x16x32_f16(a, b3, acc[nf][3], 0, 0, 0);
      }
    }
  }

#pragma unroll
  for (int nf = 0; nf < 4; ++nf)
#pragma unroll
    for (int r = 0; r < 4; ++r) {
      const int nloc = nf * 16 + lkg * 4 + r;
      const int grow = row0 + nloc;
      float sp = 0.f;
#pragma unroll
      for (int df = 0; df < 4; ++df) {
        const int dcol = col0 + df * 16 + lrow;
        const float av = acc[nf][df][r];  // P[c,d]
        const float mh = h2f(*(const unsigned short*)(
            lds + nloc * 1024 + (((dcol >> 3) ^ (nloc & 7)) << 4) + (dcol & 7) * 2));
        sp += mh * av;
        if (grow < CDIM) GH[((size_t)l * CDIM + grow) * DDIM + dcol] = f2h(2.f * av);
      }
      sp += __shfl_xor(sp, 1); sp += __shfl_xor(sp, 2);
      sp += __shfl_xor(sp, 4); sp += __shfl_xor(sp, 8);
      if (lrow == 0 && grow < CDIM) atomicAdd(SS + l * 1024 + grow, sp);
    }
}

// K2 main: m97-shape GEMM W = Fh*SY^T per 128x128 tile + fused epilogue.
// 256 thr = 4 waves (2 rowg x 2 colg), wave = 64x64, BK=32, 16 K-steps, dbuf LDS.
extern "C" __global__ __launch_bounds__(256, 3)
void mel_main(const float* __restrict__ F, const float* __restrict__ W,
              const int* __restrict__ IDX, const unsigned short* __restrict__ SY,
              const unsigned short* __restrict__ GH, const float* __restrict__ SS,
              float* __restrict__ OUT) {
  extern __shared__ __align__(16) char lds[];
  int* ids = (int*)(lds + IDS_OFF);
  float* sval = (float*)(lds + SVAL_OFF);
  float* red = (float*)(lds + RED_OFF);
  const int t = threadIdx.x, lane = t & 63, w4 = t >> 6;
  const int bid = blockIdx.x, xcd = bid & 7, l = xcd >> 1;
  const int tile = ((bid >> 3) << 1) | (xcd & 1);   // 0..511 within l
  const int n0 = (tile >> 2) * 128;                 // M-tile base row
  const int c0 = (tile & 3) * 128;                  // col-strip base
  const int wr = w4 >> 1, wc = w4 & 1;
  const int lrow = lane & 15, lkg = lane >> 4;
  const int rot = (lrow >> 1) & 3;                  // read-side granule rotate

  // ids + svals for this block's 128 rows
  if (t < 128) {
    const int cc = IDX[n0 + t];
    ids[t] = cc;
    sval[t] = SS[l * 1024 + cc];
  }

  // ---- A staging coords: thread t -> row r_st = t>>1, e-half h_st = t&1 (16 floats)
  const int r_st = t >> 1, h_st = t & 1;
  const float* fs = F + ((size_t)l * NDIM + n0 + r_st) * DDIM + h_st * 16;
  const int rot_st = (r_st >> 1) & 3;
  const int wb0 = r_st * 64 + (((2 * h_st + 0) + rot_st) & 3) * 16;
  const int wb1 = r_st * 64 + (((2 * h_st + 1) + rot_st) & 3) * 16;

  // ---- B gload coords: instr i, this lane fills phys slot (rB = i*64 + w4*16 + lane/4,
  //      gp = lane&3); it must FETCH logical granule g = (gp - rot(rB)) & 3.
  const unsigned short* sy_l = SY + ((size_t)l << 18);
  const int rB0 = w4 * 16 + (lane >> 2);
  const int rB1 = 64 + rB0;
  const int g0 = ((lane & 3) - ((rB0 >> 1) & 3)) & 3;
  const int g1 = ((lane & 3) - ((rB1 >> 1) & 3)) & 3;
  const unsigned short* bsrc0 = sy_l + (size_t)(c0 + rB0) * DDIM + g0 * 8;
  const unsigned short* bsrc1 = sy_l + (size_t)(c0 + rB1) * DDIM + g1 * 8;

  // ---- prologue: stage step 0 into buf 0
  {
    float4 a0 = *(const float4*)(fs);
    float4 a1 = *(const float4*)(fs + 4);
    float4 a2 = *(const float4*)(fs + 8);
    float4 a3 = *(const float4*)(fs + 12);
    gload16(bsrc0, lds + BB0 + w4 * 1024);
    gload16(bsrc1, lds + BB0 + 4096 + w4 * 1024);
    *(f16x8*)(lds + AB0 + wb0) = cvt8(a0, a1);
    *(f16x8*)(lds + AB0 + wb1) = cvt8(a2, a3);
  }
  __syncthreads();

  f32x4 acc[4][4];  // [nf rows][df cols]
#pragma unroll
  for (int i = 0; i < 4; ++i)
#pragma unroll
    for (int j = 0; j < 4; ++j) acc[i][j] = {0.f, 0.f, 0.f, 0.f};

#pragma unroll 2
  for (int s = 0; s < NSTEP; ++s) {
    char* ab = lds + AB0 + (s & 1) * 8192;
    char* bb = lds + BB0 + (s & 1) * 8192;
    char* abn = lds + AB0 + ((s + 1) & 1) * 8192;
    char* bbn = lds + BB0 + ((s + 1) & 1) * 8192;
    float4 a0, a1, a2, a3;
    if (s < NSTEP - 1) {  // issue next-step loads first (regs + gload_lds)
      const float* fn = fs + (s + 1) * 32;
      a0 = *(const float4*)(fn);
      a1 = *(const float4*)(fn + 4);
      a2 = *(const float4*)(fn + 8);
      a3 = *(const float4*)(fn + 12);
      gload16(bsrc0 + (s + 1) * 32, bbn + w4 * 1024);
      gload16(bsrc1 + (s + 1) * 32, bbn + 4096 + w4 * 1024);
    }
    // ds_read frags (cur) + 16 MFMA
    f16x8 af[4], bf[4];
#pragma unroll
    for (int nf = 0; nf < 4; ++nf) {
      const int row = wr * 64 + nf * 16 + lrow;
      af[nf] = *(const f16x8*)(ab + row * 64 + (((lkg + rot) & 3) << 4));
    }
#pragma unroll
    for (int df = 0; df < 4; ++df) {
      const int row = wc * 64 + df * 16 + lrow;
      bf[df] = *(const f16x8*)(bb + row * 64 + (((lkg + rot) & 3) << 4));
    }
#pragma unroll
    for (int nf = 0; nf < 4; ++nf)
#pragma unroll
      for (int df = 0; df < 4; ++df)
        acc[nf][df] = __builtin_amdgcn_mfma_f32_16x16x32_f16(af[nf], bf[df], acc[nf][df], 0, 0, 0);
    if (s < NSTEP - 1) {  // write next A tile (after MFMAs; vmcnt lands here)
      *(f16x8*)(abn + wb0) = cvt8(a0, a1);
      *(f16x8*)(abn + wb1) = cvt8(a2, a3);
    }
    __syncthreads();
  }

  // ---- epilogue: q-partial = sum_d fh*(W - GH[c,d]);  + SS[c] once (strip 0)
  const unsigned short* gh_l = GH + (size_t)l * CDIM * DDIM;
  const float* fre = F + ((size_t)l * NDIM + n0) * DDIM;
  const int strip0 = (tile & 3) == 0;
  float tsum = 0.f;
#pragma unroll
  for (int nf = 0; nf < 4; ++nf)
#pragma unroll
    for (int df = 0; df < 4; ++df) {
      const int col = c0 + wc * 64 + df * 16 + lrow;
      f32x4 cfrag = acc[nf][df];
#pragma unroll
      for (int r = 0; r < 4; ++r) {
        const int rowl = wr * 64 + nf * 16 + lkg * 4 + r;
        const float fh = fre[(size_t)rowl * DDIM + col];
        const float gh = h2f(gh_l[(size_t)ids[rowl] * DDIM + col]);
        tsum += fh * (cfrag[r] - gh);
        if (strip0 && wc == 0 && df == 0 && lrow == 0) tsum += sval[rowl];
      }
    }
#pragma unroll
  for (int off = 32; off > 0; off >>= 1) tsum += __shfl_down(tsum, off);
  __syncthreads();
  if (lane == 0) red[w4] = tsum;
  __syncthreads();
  if (t == 0)
    atomicAdd(OUT, (red[0] + red[1] + red[2] + red[3]) * (W[l] / (float)NDIM));
}

// Correct-but-slow fp32 fallback (only if ws_size < WS_NEED).
extern "C" __global__ void mel_fallback(const float* __restrict__ F,
                                        const float* __restrict__ MEAN,
                                        const float* __restrict__ IC,
                                        const float* __restrict__ W,
                                        const int* __restrict__ IDX,
                                        float* __restrict__ OUT) {
  __shared__ float v[8][DDIM];
  __shared__ float red[256];
  const int t = threadIdx.x;
  const int l = blockIdx.y;
  const int n0 = blockIdx.x * 8;
  for (int i = t; i < 8 * DDIM; i += 256) {
    int n = i >> 9, e = i & 511;
    int c = IDX[n0 + n];
    v[n][e] = F[((size_t)l * NDIM + n0 + n) * DDIM + e] -
              MEAN[((size_t)l * CDIM + c) * DDIM + e];
  }
  __syncthreads();
  const float* icl = IC + ((size_t)l << 18);
  float part = 0.f;
  for (int rep = 0; rep < 2; ++rep) {
    int d = t + rep * 256;
    float s[8];
#pragma unroll
    for (int j = 0; j < 8; ++j) s[j] = 0.f;
    for (int e = 0; e < DDIM; ++e) {
      float m = icl[(size_t)d * DDIM + e];
#pragma unroll
      for (int j = 0; j < 8; ++j) s[j] += m * v[j][e];
    }
#pragma unroll
    for (int j = 0; j < 8; ++j) part += v[j][d] * s[j];
  }
  red[t] = part;
  __syncthreads();
  for (int o = 128; o > 0; o >>= 1) {
    if (t < o) red[t] += red[t + o];
    __syncthreads();
  }
  if (t == 0) atomicAdd(OUT, red[0] * (W[l] / (float)NDIM));
}

extern "C" void kernel_launch(void* const* d_in, const int* in_sizes, int n_in,
                              void* d_out, int out_size, void* d_ws, size_t ws_size,
                              hipStream_t stream) {
  const float* F = (const float*)d_in[0];
  const float* MEAN = (const float*)d_in[1];
  const float* IC = (const float*)d_in[2];
  const float* W = (const float*)d_in[3];
  const int* IDX = (const int*)d_in[4];
  float* OUT = (float*)d_out;

  hipMemsetAsync(d_out, 0, sizeof(float) * (size_t)out_size, stream);

  if (ws_size >= WS_NEED) {
    unsigned short* SYp = (unsigned short*)d_ws;
    unsigned short* GHp = (unsigned short*)((char*)d_ws + GH_OFF);
    float* SSp = (float*)((char*)d_ws + SS_OFF);
    hipMemsetAsync(SSp, 0, SS_FLOATS * 4, stream);
    mel_mconv<<<dim3(1024), dim3(256), 0, stream>>>(IC, SYp);
    (void)hipFuncSetAttribute(reinterpret_cast<const void*>(mel_prep),
                              hipFuncAttributeMaxDynamicSharedMemorySize, LDS_PREP);
    mel_prep<<<dim3(64), dim3(512), LDS_PREP, stream>>>(MEAN, SYp, GHp, SSp);
    (void)hipFuncSetAttribute(reinterpret_cast<const void*>(mel_main),
                              hipFuncAttributeMaxDynamicSharedMemorySize, LDS_MAIN);
    mel_main<<<dim3(2048), dim3(256), LDS_MAIN, stream>>>(
        F, W, IDX, SYp, GHp, SSp, OUT);
  } else {
    mel_fallback<<<dim3(NDIM / 8, LDIM), dim3(256), 0, stream>>>(F, MEAN, IC, W, IDX, OUT);
  }
}

// Round 11
// 97.258 us; speedup vs baseline: 1.4124x; 1.4124x over previous
//
#include <hip/hip_runtime.h>
#include <hip/hip_bf16.h>
#include <stdint.h>

// MahalanobisEnsembleLoss: out = sum_l w[l] * mean_n( v^T M_l v ),  v = F[l,n,:] - MEAN[l,idx[n],:]
// Decomposition (asymmetry-correct, R8-validated):  SY = 0.5*(M + M^T) in fp16
//   q_n = f^T SY f  -  f . GH[idx_n]  +  SS[idx_n]
//   GH[c] = 2*(SY . mean[c]) (fp16),  SS[c] = mean[c]^T SY mean[c] (fp32)
// R11: SY stored K-TILED + PRE-SWIZZLED in ws: SYT[l][step][512 d][32 e], granule
// rot (g+(d>>1))&3 baked in -> B staging = contiguous coalesced global_load_lds,
// LDS reads conflict-free. BM=64 x full width (F read once), 512thr/8 waves,
// acc[4][4], dbuf LDS 72.6KB -> 2 blocks/CU. One barrier per K-step (m97 shape).
#define LDIM 4
#define NDIM 16384
#define DDIM 512
#define CDIM 1000
#define NSTEP 16

// ---- workspace layout (bytes) ----
#define SYT_ELEMS ((size_t)LDIM * DDIM * DDIM)
#define GH_OFF   (SYT_ELEMS * 2)
#define GH_ELEMS ((size_t)LDIM * CDIM * DDIM)
#define SS_OFF   (GH_OFF + GH_ELEMS * 2)
#define SS_FLOATS ((size_t)LDIM * 1024)
#define WS_NEED  (SS_OFF + SS_FLOATS * 4)   // ~6.11 MiB

typedef __attribute__((ext_vector_type(8))) _Float16 f16x8;
typedef __attribute__((ext_vector_type(4))) float f32x4;

__device__ __forceinline__ unsigned short f2h(float x) {
  union { _Float16 h; unsigned short u; } c; c.h = (_Float16)x; return c.u;
}
__device__ __forceinline__ float h2f(unsigned short u) {
  union { unsigned short u; _Float16 h; } c; c.u = u; return (float)c.h;
}
__device__ __forceinline__ f16x8 cvt8(float4 a, float4 b) {
  f16x8 p;
  p[0] = (_Float16)a.x; p[1] = (_Float16)a.y; p[2] = (_Float16)a.z; p[3] = (_Float16)a.w;
  p[4] = (_Float16)b.x; p[5] = (_Float16)b.y; p[6] = (_Float16)b.z; p[7] = (_Float16)b.w;
  return p;
}
__device__ __forceinline__ void gload16(const void* g, void* l) {
  __builtin_amdgcn_global_load_lds(
      (const __attribute__((address_space(1))) void*)g,
      (__attribute__((address_space(3))) void*)l, 16, 0, 0);
}

// SYT element offset (halfwords) for (l, row d, k): tile s=k>>5, granule g=(k&31)>>3
// pre-rotated by (d>>1)&3; within-granule (k&7).
__device__ __forceinline__ size_t syt_off(int l, int d, int k) {
  return ((size_t)(l * NSTEP + (k >> 5)) * DDIM + d) * 32 +
         ((((k & 31) >> 3) + ((d >> 1) & 3)) & 3) * 8 + (k & 7);
}

// ---- main LDS: B dbuf 2x32KB | A dbuf 2x4KB | ids[64] | sval[64] | red[8]
#define BB0 0
#define AB0 65536
#define IDS_OFF 73728
#define SVAL_OFF 73984
#define RED_OFF 74240
#define LDS_MAIN 74272
#define LDS_PREP 65536

// K0: SYT = K-tiled, pre-swizzled fp16(0.5*(M+M^T)).
extern "C" __global__ void mel_mconv(const float* __restrict__ IC,
                                     unsigned short* __restrict__ SYT) {
  size_t i4 = (size_t)blockIdx.x * 256 + threadIdx.x;  // covers L*D*D/4
  size_t base = i4 * 4;
  int l = (int)(base >> 18);
  int rem = (int)(base & 262143);
  int d = rem >> 9;
  int e = rem & 511;
  float4 v = *(const float4*)(IC + base);
  const float* icl = IC + ((size_t)l << 18);
  float t0 = icl[(size_t)(e + 0) * DDIM + d];
  float t1 = icl[(size_t)(e + 1) * DDIM + d];
  float t2 = icl[(size_t)(e + 2) * DDIM + d];
  float t3 = icl[(size_t)(e + 3) * DDIM + d];
  *(ushort4*)(SYT + syt_off(l, d, e)) =
      make_ushort4(f2h(0.5f * (v.x + t0)), f2h(0.5f * (v.y + t1)),
                   f2h(0.5f * (v.z + t2)), f2h(0.5f * (v.w + t3)));
}

// K1: P = meanh . SY^T ; GH[c,:] = fp16(2P), SS[c] = sum_d meanh*P. 64 blocks x 512 thr.
extern "C" __global__ __launch_bounds__(512, 2)
void mel_prep(const float* __restrict__ MEAN, const unsigned short* __restrict__ SYT,
              unsigned short* __restrict__ GH, float* __restrict__ SS) {
  extern __shared__ __align__(16) char lds[];
  const int t = threadIdx.x, lane = t & 63, w = t >> 6;
  const int l = blockIdx.x & 3, ct = blockIdx.x >> 2;
  const int row0 = ct * 64;
  const int col0 = w * 64, lrow = lane & 15, lkg = lane >> 4;
  const int lke = lkg << 3;

  {  // stage 64 mean rows as fp16 (rows >= CDIM -> 0); [64][512] XOR-granule layout
    const int srow = t >> 3;
    const int grow = row0 + srow;
    const float* mr = MEAN + ((size_t)l * CDIM + grow) * DDIM + ((t & 7) << 3);
    const int swb = srow * 1024 + (((t & 7) ^ (srow & 7)) << 4);
    const float4 z4 = {0.f, 0.f, 0.f, 0.f};
    for (int c = 0; c < 8; ++c) {
      float4 x = z4, y = z4;
      if (grow < CDIM) { x = *(const float4*)(mr + c * 64); y = *(const float4*)(mr + c * 64 + 4); }
      *(f16x8*)(lds + swb + c * 128) = cvt8(x, y);
    }
  }
  __syncthreads();

  f32x4 acc[4][4];
#pragma unroll
  for (int i = 0; i < 4; ++i)
#pragma unroll
    for (int j = 0; j < 4; ++j) acc[i][j] = {0.f, 0.f, 0.f, 0.f};

  for (int c = 0; c < 8; ++c) {
#pragma unroll
    for (int ks = 0; ks < 2; ++ks) {
      const int k = c * 64 + ks * 32 + lke;
      f16x8 b0 = *(const f16x8*)(SYT + syt_off(l, col0 + lrow, k));
      f16x8 b1 = *(const f16x8*)(SYT + syt_off(l, col0 + 16 + lrow, k));
      f16x8 b2 = *(const f16x8*)(SYT + syt_off(l, col0 + 32 + lrow, k));
      f16x8 b3 = *(const f16x8*)(SYT + syt_off(l, col0 + 48 + lrow, k));
      const int xo = c * 128 + ((((ks << 2) + lkg) ^ (lrow & 7)) << 4);
      f16x8 a0 = *(const f16x8*)(lds + lrow * 1024 + xo);
      f16x8 a1 = *(const f16x8*)(lds + (16 + lrow) * 1024 + xo);
      f16x8 a2 = *(const f16x8*)(lds + (32 + lrow) * 1024 + xo);
      f16x8 a3 = *(const f16x8*)(lds + (48 + lrow) * 1024 + xo);
#pragma unroll
      for (int nf = 0; nf < 4; ++nf) {
        f16x8 a = nf == 0 ? a0 : nf == 1 ? a1 : nf == 2 ? a2 : a3;
        acc[nf][0] = __builtin_amdgcn_mfma_f32_16x16x32_f16(a, b0, acc[nf][0], 0, 0, 0);
        acc[nf][1] = __builtin_amdgcn_mfma_f32_16x16x32_f16(a, b1, acc[nf][1], 0, 0, 0);
        acc[nf][2] = __builtin_amdgcn_mfma_f32_16x16x32_f16(a, b2, acc[nf][2], 0, 0, 0);
        acc[nf][3] = __builtin_amdgcn_mfma_f32_16x16x32_f16(a, b3, acc[nf][3], 0, 0, 0);
      }
    }
  }

#pragma unroll
  for (int nf = 0; nf < 4; ++nf)
#pragma unroll
    for (int r = 0; r < 4; ++r) {
      const int nloc = nf * 16 + lkg * 4 + r;
      const int grow = row0 + nloc;
      float sp = 0.f;
#pragma unroll
      for (int df = 0; df < 4; ++df) {
        const int dcol = col0 + df * 16 + lrow;
        const float av = acc[nf][df][r];  // P[c,d]
        const float mh = h2f(*(const unsigned short*)(
            lds + nloc * 1024 + (((dcol >> 3) ^ (nloc & 7)) << 4) + (dcol & 7) * 2));
        sp += mh * av;
        if (grow < CDIM) GH[((size_t)l * CDIM + grow) * DDIM + dcol] = f2h(2.f * av);
      }
      sp += __shfl_xor(sp, 1); sp += __shfl_xor(sp, 2);
      sp += __shfl_xor(sp, 4); sp += __shfl_xor(sp, 8);
      if (lrow == 0 && grow < CDIM) atomicAdd(SS + l * 1024 + grow, sp);
    }
}

// K2 main: 64-row x 512-col tile. B staged contiguous via global_load_lds from SYT,
// A staged per-step from F (fp32->fp16). acc[4][4] per wave (64x64). 2 blocks/CU.
extern "C" __global__ __launch_bounds__(512, 4)
void mel_main(const float* __restrict__ F, const float* __restrict__ W,
              const int* __restrict__ IDX, const unsigned short* __restrict__ SYT,
              const unsigned short* __restrict__ GH, const float* __restrict__ SS,
              float* __restrict__ OUT) {
  extern __shared__ __align__(16) char lds[];
  int* ids = (int*)(lds + IDS_OFF);
  float* sval = (float*)(lds + SVAL_OFF);
  float* red = (float*)(lds + RED_OFF);
  const int t = threadIdx.x, lane = t & 63, w = t >> 6;  // 8 waves
  const int bid = blockIdx.x, xcd = bid & 7, l = xcd >> 1;
  const int bx = ((bid >> 3) << 1) | (xcd & 1);  // 0..255 within l
  const int n0 = bx * 64;
  const int col0 = w * 64;                        // wave's 64 cols
  const int lrow = lane & 15, lkg = lane >> 4;

  if (t < 64) {
    const int cc = IDX[n0 + t];
    ids[t] = cc;
    sval[t] = SS[l * 1024 + cc];
  }

  // A staging coords: thread -> row t>>3, e_loc (t&7)*4 within BK=32 chunk
  const int a_row = t >> 3, a_el = (t & 7) << 2;
  const float* fA = F + ((size_t)l * NDIM + n0 + a_row) * DDIM + a_el;
  const int a_wb = a_row * 64 + ((((a_el >> 3) + ((a_row >> 1) & 3)) & 3) << 4) +
                   ((a_el & 7) << 1);
  // B staging: 4 gload16/thread; slot i*512+t of the contiguous 32KB step-tile.
  const unsigned short* syt_l = SYT + (size_t)l * NSTEP * DDIM * 32;

  {  // prologue: stage step 0 into buf 0
#pragma unroll
    for (int i = 0; i < 4; ++i)
      gload16(syt_l + (size_t)(i * 512 + t) * 8,
              lds + BB0 + ((i * 512 + (t & ~63)) << 4));
    float4 x = *(const float4*)(fA);
    ushort4 h = make_ushort4(f2h(x.x), f2h(x.y), f2h(x.z), f2h(x.w));
    *(ushort4*)(lds + AB0 + a_wb) = h;
  }
  __syncthreads();

  f32x4 acc[4][4];  // [nf rows][df cols]
#pragma unroll
  for (int i = 0; i < 4; ++i)
#pragma unroll
    for (int j = 0; j < 4; ++j) acc[i][j] = {0.f, 0.f, 0.f, 0.f};

#pragma unroll 2
  for (int s = 0; s < NSTEP; ++s) {
    char* bb = lds + BB0 + (s & 1) * 32768;
    char* ab = lds + AB0 + (s & 1) * 4096;
    char* bbn = lds + BB0 + ((s + 1) & 1) * 32768;
    char* abn = lds + AB0 + ((s + 1) & 1) * 4096;
    float4 x;
    if (s < NSTEP - 1) {  // issue next-step loads first
      const unsigned short* src = syt_l + (size_t)(s + 1) * DDIM * 32;
#pragma unroll
      for (int i = 0; i < 4; ++i)
        gload16(src + (size_t)(i * 512 + t) * 8,
                bbn + ((i * 512 + (t & ~63)) << 4));
      x = *(const float4*)(fA + (s + 1) * 32);
    }
    // ds_read frags + 16 MFMA
    f16x8 af[4], bf[4];
#pragma unroll
    for (int nf = 0; nf < 4; ++nf) {
      const int row = nf * 16 + lrow;
      af[nf] = *(const f16x8*)(ab + row * 64 + (((lkg + ((row >> 1) & 3)) & 3) << 4));
    }
#pragma unroll
    for (int df = 0; df < 4; ++df) {
      const int row = col0 + df * 16 + lrow;
      bf[df] = *(const f16x8*)(bb + row * 64 + (((lkg + ((row >> 1) & 3)) & 3) << 4));
    }
#pragma unroll
    for (int nf = 0; nf < 4; ++nf)
#pragma unroll
      for (int df = 0; df < 4; ++df)
        acc[nf][df] = __builtin_amdgcn_mfma_f32_16x16x32_f16(af[nf], bf[df], acc[nf][df], 0, 0, 0);
    if (s < NSTEP - 1) {  // write next A chunk (vmcnt wait for x lands here)
      ushort4 h = make_ushort4(f2h(x.x), f2h(x.y), f2h(x.z), f2h(x.w));
      *(ushort4*)(abn + a_wb) = h;
    }
    __syncthreads();
  }

  // ---- epilogue: q-partial = sum_d fh*(W[n,d] - GH[c,d]); + SS[c] once (wave 0)
  const unsigned short* gh_l = GH + (size_t)l * CDIM * DDIM;
  const float* fre = F + ((size_t)l * NDIM + n0) * DDIM;
  float tsum = 0.f;
#pragma unroll
  for (int nf = 0; nf < 4; ++nf)
#pragma unroll
    for (int df = 0; df < 4; ++df) {
      const int col = col0 + df * 16 + lrow;
      f32x4 cfrag = acc[nf][df];
#pragma unroll
      for (int r = 0; r < 4; ++r) {
        const int rowl = nf * 16 + lkg * 4 + r;
        const float fh = fre[(size_t)rowl * DDIM + col];
        const float gh = h2f(gh_l[(size_t)ids[rowl] * DDIM + col]);
        tsum += fh * (cfrag[r] - gh);
        if (w == 0 && df == 0 && lrow == 0) tsum += sval[rowl];
      }
    }
#pragma unroll
  for (int off = 32; off > 0; off >>= 1) tsum += __shfl_down(tsum, off);
  __syncthreads();
  if (lane == 0) red[w] = tsum;
  __syncthreads();
  if (t == 0) {
    float ssum = 0.f;
#pragma unroll
    for (int i = 0; i < 8; ++i) ssum += red[i];
    atomicAdd(OUT, ssum * (W[l] / (float)NDIM));
  }
}

// Correct-but-slow fp32 fallback (only if ws_size < WS_NEED).
extern "C" __global__ void mel_fallback(const float* __restrict__ F,
                                        const float* __restrict__ MEAN,
                                        const float* __restrict__ IC,
                                        const float* __restrict__ W,
                                        const int* __restrict__ IDX,
                                        float* __restrict__ OUT) {
  __shared__ float v[8][DDIM];
  __shared__ float red[256];
  const int t = threadIdx.x;
  const int l = blockIdx.y;
  const int n0 = blockIdx.x * 8;
  for (int i = t; i < 8 * DDIM; i += 256) {
    int n = i >> 9, e = i & 511;
    int c = IDX[n0 + n];
    v[n][e] = F[((size_t)l * NDIM + n0 + n) * DDIM + e] -
              MEAN[((size_t)l * CDIM + c) * DDIM + e];
  }
  __syncthreads();
  const float* icl = IC + ((size_t)l << 18);
  float part = 0.f;
  for (int rep = 0; rep < 2; ++rep) {
    int d = t + rep * 256;
    float s[8];
#pragma unroll
    for (int j = 0; j < 8; ++j) s[j] = 0.f;
    for (int e = 0; e < DDIM; ++e) {
      float m = icl[(size_t)d * DDIM + e];
#pragma unroll
      for (int j = 0; j < 8; ++j) s[j] += m * v[j][e];
    }
#pragma unroll
    for (int j = 0; j < 8; ++j) part += v[j][d] * s[j];
  }
  red[t] = part;
  __syncthreads();
  for (int o = 128; o > 0; o >>= 1) {
    if (t < o) red[t] += red[t + o];
    __syncthreads();
  }
  if (t == 0) atomicAdd(OUT, red[0] * (W[l] / (float)NDIM));
}

extern "C" void kernel_launch(void* const* d_in, const int* in_sizes, int n_in,
                              void* d_out, int out_size, void* d_ws, size_t ws_size,
                              hipStream_t stream) {
  const float* F = (const float*)d_in[0];
  const float* MEAN = (const float*)d_in[1];
  const float* IC = (const float*)d_in[2];
  const float* W = (const float*)d_in[3];
  const int* IDX = (const int*)d_in[4];
  float* OUT = (float*)d_out;

  hipMemsetAsync(d_out, 0, sizeof(float) * (size_t)out_size, stream);

  if (ws_size >= WS_NEED) {
    unsigned short* SYTp = (unsigned short*)d_ws;
    unsigned short* GHp = (unsigned short*)((char*)d_ws + GH_OFF);
    float* SSp = (float*)((char*)d_ws + SS_OFF);
    hipMemsetAsync(SSp, 0, SS_FLOATS * 4, stream);
    mel_mconv<<<dim3(1024), dim3(256), 0, stream>>>(IC, SYTp);
    (void)hipFuncSetAttribute(reinterpret_cast<const void*>(mel_prep),
                              hipFuncAttributeMaxDynamicSharedMemorySize, LDS_PREP);
    mel_prep<<<dim3(64), dim3(512), LDS_PREP, stream>>>(MEAN, SYTp, GHp, SSp);
    (void)hipFuncSetAttribute(reinterpret_cast<const void*>(mel_main),
                              hipFuncAttributeMaxDynamicSharedMemorySize, LDS_MAIN);
    mel_main<<<dim3(1024), dim3(512), LDS_MAIN, stream>>>(
        F, W, IDX, SYTp, GHp, SSp, OUT);
  } else {
    mel_fallback<<<dim3(NDIM / 8, LDIM), dim3(256), 0, stream>>>(F, MEAN, IC, W, IDX, OUT);
  }
}

// Round 12
// 96.642 us; speedup vs baseline: 1.4214x; 1.0064x over previous
//
#include <hip/hip_runtime.h>
#include <hip/hip_bf16.h>
#include <stdint.h>

// MahalanobisEnsembleLoss: out = sum_l w[l] * mean_n( v^T M_l v ),  v = F[l,n,:] - MEAN[l,idx[n],:]
// Decomposition (asymmetry-correct, R8-validated):  SY = 0.5*(M + M^T) in fp16
//   q_n = f^T SY f  -  f . GH[idx_n]  +  SS[idx_n]
//   GH[c] = 2*(SY . mean[c]) (fp16),  SS[c] = mean[c]^T SY mean[c] (fp32)
// R12: waves own disjoint 64-col slices -> B is wave-private. B-frags read DIRECTLY
// from K-tiled pre-swizzled SYT in L2 (1KB coalesced per instr, formula verified via
// mel_prep). A staged ONCE up front (burst MLP), 16-chunk swizzled LDS image.
// K-loop: ZERO barriers, zero asm -> compiler pipelines B freely; TLP covers L2 lat.
#define LDIM 4
#define NDIM 16384
#define DDIM 512
#define CDIM 1000
#define NSTEP 16

// ---- workspace layout (bytes) ----
#define SYT_ELEMS ((size_t)LDIM * DDIM * DDIM)
#define GH_OFF   (SYT_ELEMS * 2)
#define GH_ELEMS ((size_t)LDIM * CDIM * DDIM)
#define SS_OFF   (GH_OFF + GH_ELEMS * 2)
#define SS_FLOATS ((size_t)LDIM * 1024)
#define WS_NEED  (SS_OFF + SS_FLOATS * 4)   // ~6.11 MiB

typedef __attribute__((ext_vector_type(8))) _Float16 f16x8;
typedef __attribute__((ext_vector_type(4))) float f32x4;

__device__ __forceinline__ unsigned short f2h(float x) {
  union { _Float16 h; unsigned short u; } c; c.h = (_Float16)x; return c.u;
}
__device__ __forceinline__ float h2f(unsigned short u) {
  union { unsigned short u; _Float16 h; } c; c.u = u; return (float)c.h;
}
__device__ __forceinline__ f16x8 cvt8(float4 a, float4 b) {
  f16x8 p;
  p[0] = (_Float16)a.x; p[1] = (_Float16)a.y; p[2] = (_Float16)a.z; p[3] = (_Float16)a.w;
  p[4] = (_Float16)b.x; p[5] = (_Float16)b.y; p[6] = (_Float16)b.z; p[7] = (_Float16)b.w;
  return p;
}

// SYT element offset (halfwords) for (l, row d, k): tile s=k>>5, granule g=(k&31)>>3
// pre-rotated by (d>>1)&3; within-granule (k&7).   [verified R11 end-to-end]
__device__ __forceinline__ size_t syt_off(int l, int d, int k) {
  return ((size_t)(l * NSTEP + (k >> 5)) * DDIM + d) * 32 +
         ((((k & 31) >> 3) + ((d >> 1) & 3)) & 3) * 8 + (k & 7);
}

// ---- main LDS: A image 16 chunks x [64 rows][32 e] (rot-granule swizzled) | tables
#define IDS_OFF 65536
#define SVAL_OFF 65792
#define RED_OFF 66048
#define LDS_MAIN 66080
#define LDS_PREP 65536

// K0: SYT = K-tiled, pre-swizzled fp16(0.5*(M+M^T)).
extern "C" __global__ void mel_mconv(const float* __restrict__ IC,
                                     unsigned short* __restrict__ SYT) {
  size_t i4 = (size_t)blockIdx.x * 256 + threadIdx.x;  // covers L*D*D/4
  size_t base = i4 * 4;
  int l = (int)(base >> 18);
  int rem = (int)(base & 262143);
  int d = rem >> 9;
  int e = rem & 511;
  float4 v = *(const float4*)(IC + base);
  const float* icl = IC + ((size_t)l << 18);
  float t0 = icl[(size_t)(e + 0) * DDIM + d];
  float t1 = icl[(size_t)(e + 1) * DDIM + d];
  float t2 = icl[(size_t)(e + 2) * DDIM + d];
  float t3 = icl[(size_t)(e + 3) * DDIM + d];
  *(ushort4*)(SYT + syt_off(l, d, e)) =
      make_ushort4(f2h(0.5f * (v.x + t0)), f2h(0.5f * (v.y + t1)),
                   f2h(0.5f * (v.z + t2)), f2h(0.5f * (v.w + t3)));
}

// K1: P = meanh . SY^T ; GH[c,:] = fp16(2P), SS[c] = sum_d meanh*P. 64 blocks x 512 thr.
extern "C" __global__ __launch_bounds__(512, 2)
void mel_prep(const float* __restrict__ MEAN, const unsigned short* __restrict__ SYT,
              unsigned short* __restrict__ GH, float* __restrict__ SS) {
  extern __shared__ __align__(16) char lds[];
  const int t = threadIdx.x, lane = t & 63, w = t >> 6;
  const int l = blockIdx.x & 3, ct = blockIdx.x >> 2;
  const int row0 = ct * 64;
  const int col0 = w * 64, lrow = lane & 15, lkg = lane >> 4;
  const int lke = lkg << 3;

  {  // stage 64 mean rows as fp16 (rows >= CDIM -> 0); [64][512] XOR-granule layout
    const int srow = t >> 3;
    const int grow = row0 + srow;
    const float* mr = MEAN + ((size_t)l * CDIM + grow) * DDIM + ((t & 7) << 3);
    const int swb = srow * 1024 + (((t & 7) ^ (srow & 7)) << 4);
    const float4 z4 = {0.f, 0.f, 0.f, 0.f};
    for (int c = 0; c < 8; ++c) {
      float4 x = z4, y = z4;
      if (grow < CDIM) { x = *(const float4*)(mr + c * 64); y = *(const float4*)(mr + c * 64 + 4); }
      *(f16x8*)(lds + swb + c * 128) = cvt8(x, y);
    }
  }
  __syncthreads();

  f32x4 acc[4][4];
#pragma unroll
  for (int i = 0; i < 4; ++i)
#pragma unroll
    for (int j = 0; j < 4; ++j) acc[i][j] = {0.f, 0.f, 0.f, 0.f};

  for (int c = 0; c < 8; ++c) {
#pragma unroll
    for (int ks = 0; ks < 2; ++ks) {
      const int k = c * 64 + ks * 32 + lke;
      f16x8 b0 = *(const f16x8*)(SYT + syt_off(l, col0 + lrow, k));
      f16x8 b1 = *(const f16x8*)(SYT + syt_off(l, col0 + 16 + lrow, k));
      f16x8 b2 = *(const f16x8*)(SYT + syt_off(l, col0 + 32 + lrow, k));
      f16x8 b3 = *(const f16x8*)(SYT + syt_off(l, col0 + 48 + lrow, k));
      const int xo = c * 128 + ((((ks << 2) + lkg) ^ (lrow & 7)) << 4);
      f16x8 a0 = *(const f16x8*)(lds + lrow * 1024 + xo);
      f16x8 a1 = *(const f16x8*)(lds + (16 + lrow) * 1024 + xo);
      f16x8 a2 = *(const f16x8*)(lds + (32 + lrow) * 1024 + xo);
      f16x8 a3 = *(const f16x8*)(lds + (48 + lrow) * 1024 + xo);
#pragma unroll
      for (int nf = 0; nf < 4; ++nf) {
        f16x8 a = nf == 0 ? a0 : nf == 1 ? a1 : nf == 2 ? a2 : a3;
        acc[nf][0] = __builtin_amdgcn_mfma_f32_16x16x32_f16(a, b0, acc[nf][0], 0, 0, 0);
        acc[nf][1] = __builtin_amdgcn_mfma_f32_16x16x32_f16(a, b1, acc[nf][1], 0, 0, 0);
        acc[nf][2] = __builtin_amdgcn_mfma_f32_16x16x32_f16(a, b2, acc[nf][2], 0, 0, 0);
        acc[nf][3] = __builtin_amdgcn_mfma_f32_16x16x32_f16(a, b3, acc[nf][3], 0, 0, 0);
      }
    }
  }

#pragma unroll
  for (int nf = 0; nf < 4; ++nf)
#pragma unroll
    for (int r = 0; r < 4; ++r) {
      const int nloc = nf * 16 + lkg * 4 + r;
      const int grow = row0 + nloc;
      float sp = 0.f;
#pragma unroll
      for (int df = 0; df < 4; ++df) {
        const int dcol = col0 + df * 16 + lrow;
        const float av = acc[nf][df][r];  // P[c,d]
        const float mh = h2f(*(const unsigned short*)(
            lds + nloc * 1024 + (((dcol >> 3) ^ (nloc & 7)) << 4) + (dcol & 7) * 2));
        sp += mh * av;
        if (grow < CDIM) GH[((size_t)l * CDIM + grow) * DDIM + dcol] = f2h(2.f * av);
      }
      sp += __shfl_xor(sp, 1); sp += __shfl_xor(sp, 2);
      sp += __shfl_xor(sp, 4); sp += __shfl_xor(sp, 8);
      if (lrow == 0 && grow < CDIM) atomicAdd(SS + l * 1024 + grow, sp);
    }
}

// K2 main: A burst-staged once into 64KB LDS image; barrier-free K-loop with
// wave-private B read straight from SYT (L2). 512 thr / 8 waves; 2 blocks/CU.
extern "C" __global__ __launch_bounds__(512, 4)
void mel_main(const float* __restrict__ F, const float* __restrict__ W,
              const int* __restrict__ IDX, const unsigned short* __restrict__ SYT,
              const unsigned short* __restrict__ GH, const float* __restrict__ SS,
              float* __restrict__ OUT) {
  extern __shared__ __align__(16) char lds[];
  int* ids = (int*)(lds + IDS_OFF);
  float* sval = (float*)(lds + SVAL_OFF);
  float* red = (float*)(lds + RED_OFF);
  const int t = threadIdx.x, lane = t & 63, w = t >> 6;  // 8 waves
  const int bid = blockIdx.x, xcd = bid & 7, l = xcd >> 1;
  const int bx = ((bid >> 3) << 1) | (xcd & 1);  // 0..255 within l
  const int n0 = bx * 64;
  const int col0 = w * 64;                        // wave's 64 cols
  const int lrow = lane & 15, lkg = lane >> 4;

  if (t < 64) {
    const int cc = IDX[n0 + t];
    ids[t] = cc;
    sval[t] = SS[l * 1024 + cc];
  }

  // ---- one-shot burst A staging: row t>>3, e-quad (t&7)*4 in each of 16 chunks
  const int a_row = t >> 3, a_el = (t & 7) << 2;
  const float* fA = F + ((size_t)l * NDIM + n0 + a_row) * DDIM + a_el;
  const int a_wb = a_row * 64 + ((((a_el >> 3) + ((a_row >> 1) & 3)) & 3) << 4) +
                   ((a_el & 7) << 1);
  {
    float4 fv[16];
#pragma unroll
    for (int c = 0; c < 16; ++c) fv[c] = *(const float4*)(fA + c * 32);
#pragma unroll
    for (int c = 0; c < 16; ++c) {
      ushort4 h = make_ushort4(f2h(fv[c].x), f2h(fv[c].y), f2h(fv[c].z), f2h(fv[c].w));
      *(ushort4*)(lds + c * 4096 + a_wb) = h;
    }
  }
  __syncthreads();  // the ONLY barrier before the epilogue

  f32x4 acc[4][4];  // [nf rows][df cols]
#pragma unroll
  for (int i = 0; i < 4; ++i)
#pragma unroll
    for (int j = 0; j < 4; ++j) acc[i][j] = {0.f, 0.f, 0.f, 0.f};

  // ---- barrier-free K-loop: af from LDS image, bf direct from SYT (L2)
#pragma unroll 4
  for (int s = 0; s < NSTEP; ++s) {
    f16x8 bf[4], af[4];
#pragma unroll
    for (int df = 0; df < 4; ++df)
      bf[df] = *(const f16x8*)(SYT + syt_off(l, col0 + df * 16 + lrow, s * 32 + lkg * 8));
#pragma unroll
    for (int nf = 0; nf < 4; ++nf) {
      const int row = nf * 16 + lrow;
      af[nf] = *(const f16x8*)(lds + s * 4096 + row * 64 +
                               (((lkg + ((row >> 1) & 3)) & 3) << 4));
    }
#pragma unroll
    for (int nf = 0; nf < 4; ++nf)
#pragma unroll
      for (int df = 0; df < 4; ++df)
        acc[nf][df] = __builtin_amdgcn_mfma_f32_16x16x32_f16(af[nf], bf[df], acc[nf][df], 0, 0, 0);
  }

  // ---- epilogue: q-partial = sum_d fh*(W[n,d] - GH[c,d]); + SS[c] once (wave 0)
  const unsigned short* gh_l = GH + (size_t)l * CDIM * DDIM;
  const float* fre = F + ((size_t)l * NDIM + n0) * DDIM;
  float tsum = 0.f;
#pragma unroll
  for (int nf = 0; nf < 4; ++nf)
#pragma unroll
    for (int df = 0; df < 4; ++df) {
      const int col = col0 + df * 16 + lrow;
      f32x4 cfrag = acc[nf][df];
#pragma unroll
      for (int r = 0; r < 4; ++r) {
        const int rowl = nf * 16 + lkg * 4 + r;
        const float fh = fre[(size_t)rowl * DDIM + col];
        const float gh = h2f(gh_l[(size_t)ids[rowl] * DDIM + col]);
        tsum += fh * (cfrag[r] - gh);
        if (w == 0 && df == 0 && lrow == 0) tsum += sval[rowl];
      }
    }
#pragma unroll
  for (int off = 32; off > 0; off >>= 1) tsum += __shfl_down(tsum, off);
  __syncthreads();
  if (lane == 0) red[w] = tsum;
  __syncthreads();
  if (t == 0) {
    float ssum = 0.f;
#pragma unroll
    for (int i = 0; i < 8; ++i) ssum += red[i];
    atomicAdd(OUT, ssum * (W[l] / (float)NDIM));
  }
}

// Correct-but-slow fp32 fallback (only if ws_size < WS_NEED).
extern "C" __global__ void mel_fallback(const float* __restrict__ F,
                                        const float* __restrict__ MEAN,
                                        const float* __restrict__ IC,
                                        const float* __restrict__ W,
                                        const int* __restrict__ IDX,
                                        float* __restrict__ OUT) {
  __shared__ float v[8][DDIM];
  __shared__ float red[256];
  const int t = threadIdx.x;
  const int l = blockIdx.y;
  const int n0 = blockIdx.x * 8;
  for (int i = t; i < 8 * DDIM; i += 256) {
    int n = i >> 9, e = i & 511;
    int c = IDX[n0 + n];
    v[n][e] = F[((size_t)l * NDIM + n0 + n) * DDIM + e] -
              MEAN[((size_t)l * CDIM + c) * DDIM + e];
  }
  __syncthreads();
  const float* icl = IC + ((size_t)l << 18);
  float part = 0.f;
  for (int rep = 0; rep < 2; ++rep) {
    int d = t + rep * 256;
    float s[8];
#pragma unroll
    for (int j = 0; j < 8; ++j) s[j] = 0.f;
    for (int e = 0; e < DDIM; ++e) {
      float m = icl[(size_t)d * DDIM + e];
#pragma unroll
      for (int j = 0; j < 8; ++j) s[j] += m * v[j][e];
    }
#pragma unroll
    for (int j = 0; j < 8; ++j) part += v[j][d] * s[j];
  }
  red[t] = part;
  __syncthreads();
  for (int o = 128; o > 0; o >>= 1) {
    if (t < o) red[t] += red[t + o];
    __syncthreads();
  }
  if (t == 0) atomicAdd(OUT, red[0] * (W[l] / (float)NDIM));
}

extern "C" void kernel_launch(void* const* d_in, const int* in_sizes, int n_in,
                              void* d_out, int out_size, void* d_ws, size_t ws_size,
                              hipStream_t stream) {
  const float* F = (const float*)d_in[0];
  const float* MEAN = (const float*)d_in[1];
  const float* IC = (const float*)d_in[2];
  const float* W = (const float*)d_in[3];
  const int* IDX = (const int*)d_in[4];
  float* OUT = (float*)d_out;

  hipMemsetAsync(d_out, 0, sizeof(float) * (size_t)out_size, stream);

  if (ws_size >= WS_NEED) {
    unsigned short* SYTp = (unsigned short*)d_ws;
    unsigned short* GHp = (unsigned short*)((char*)d_ws + GH_OFF);
    float* SSp = (float*)((char*)d_ws + SS_OFF);
    hipMemsetAsync(SSp, 0, SS_FLOATS * 4, stream);
    mel_mconv<<<dim3(1024), dim3(256), 0, stream>>>(IC, SYTp);
    (void)hipFuncSetAttribute(reinterpret_cast<const void*>(mel_prep),
                              hipFuncAttributeMaxDynamicSharedMemorySize, LDS_PREP);
    mel_prep<<<dim3(64), dim3(512), LDS_PREP, stream>>>(MEAN, SYTp, GHp, SSp);
    (void)hipFuncSetAttribute(reinterpret_cast<const void*>(mel_main),
                              hipFuncAttributeMaxDynamicSharedMemorySize, LDS_MAIN);
    mel_main<<<dim3(1024), dim3(512), LDS_MAIN, stream>>>(
        F, W, IDX, SYTp, GHp, SSp, OUT);
  } else {
    mel_fallback<<<dim3(NDIM / 8, LDIM), dim3(256), 0, stream>>>(F, MEAN, IC, W, IDX, OUT);
  }
}

// Round 13
// 87.824 us; speedup vs baseline: 1.5641x; 1.1004x over previous
//
#include <hip/hip_runtime.h>
#include <hip/hip_bf16.h>
#include <stdint.h>

// MahalanobisEnsembleLoss: out = sum_l w[l] * mean_n( v^T M_l v ),  v = F[l,n,:] - MEAN[l,idx[n],:]
// Decomposition (asymmetry-correct, R8-validated):  SY = 0.5*(M + M^T) in fp16
//   q_n = f^T SY f  -  f . GH[idx_n]  +  SS[idx_n]
//   GH[c] = 2*(SY . mean[c]) (fp16),  SS[c] = mean[c]^T SY mean[c] (fp32)
// R13: quarter-pipelined A staging (load q+1 || compute q, 4 barriers total) to spread
// HBM demand across block life (fix 20% duty -> 1.5TB/s cap seen in R11/R12);
// epilogue fh read from the LDS A-image (no F re-read). B direct from SYT (R12).
#define LDIM 4
#define NDIM 16384
#define DDIM 512
#define CDIM 1000
#define NSTEP 16

// ---- workspace layout (bytes) ----
#define SYT_ELEMS ((size_t)LDIM * DDIM * DDIM)
#define GH_OFF   (SYT_ELEMS * 2)
#define GH_ELEMS ((size_t)LDIM * CDIM * DDIM)
#define SS_OFF   (GH_OFF + GH_ELEMS * 2)
#define SS_FLOATS ((size_t)LDIM * 1024)
#define WS_NEED  (SS_OFF + SS_FLOATS * 4)   // ~6.11 MiB

typedef __attribute__((ext_vector_type(8))) _Float16 f16x8;
typedef __attribute__((ext_vector_type(4))) float f32x4;

__device__ __forceinline__ unsigned short f2h(float x) {
  union { _Float16 h; unsigned short u; } c; c.h = (_Float16)x; return c.u;
}
__device__ __forceinline__ float h2f(unsigned short u) {
  union { unsigned short u; _Float16 h; } c; c.u = u; return (float)c.h;
}
__device__ __forceinline__ f16x8 cvt8(float4 a, float4 b) {
  f16x8 p;
  p[0] = (_Float16)a.x; p[1] = (_Float16)a.y; p[2] = (_Float16)a.z; p[3] = (_Float16)a.w;
  p[4] = (_Float16)b.x; p[5] = (_Float16)b.y; p[6] = (_Float16)b.z; p[7] = (_Float16)b.w;
  return p;
}

// SYT element offset (halfwords) for (l, row d, k): tile s=k>>5, granule g=(k&31)>>3
// pre-rotated by (d>>1)&3; within-granule (k&7).   [verified R11/R12 end-to-end]
__device__ __forceinline__ size_t syt_off(int l, int d, int k) {
  return ((size_t)(l * NSTEP + (k >> 5)) * DDIM + d) * 32 +
         ((((k & 31) >> 3) + ((d >> 1) & 3)) & 3) * 8 + (k & 7);
}

// ---- main LDS: A image 16 chunks x [64 rows][32 e] (rot-granule swizzled) | tables
#define IDS_OFF 65536
#define SVAL_OFF 65792
#define RED_OFF 66048
#define LDS_MAIN 66080
#define LDS_PREP 65536

// K0: SYT = K-tiled, pre-swizzled fp16(0.5*(M+M^T)).
extern "C" __global__ void mel_mconv(const float* __restrict__ IC,
                                     unsigned short* __restrict__ SYT) {
  size_t i4 = (size_t)blockIdx.x * 256 + threadIdx.x;  // covers L*D*D/4
  size_t base = i4 * 4;
  int l = (int)(base >> 18);
  int rem = (int)(base & 262143);
  int d = rem >> 9;
  int e = rem & 511;
  float4 v = *(const float4*)(IC + base);
  const float* icl = IC + ((size_t)l << 18);
  float t0 = icl[(size_t)(e + 0) * DDIM + d];
  float t1 = icl[(size_t)(e + 1) * DDIM + d];
  float t2 = icl[(size_t)(e + 2) * DDIM + d];
  float t3 = icl[(size_t)(e + 3) * DDIM + d];
  *(ushort4*)(SYT + syt_off(l, d, e)) =
      make_ushort4(f2h(0.5f * (v.x + t0)), f2h(0.5f * (v.y + t1)),
                   f2h(0.5f * (v.z + t2)), f2h(0.5f * (v.w + t3)));
}

// K1: P = meanh . SY^T ; GH[c,:] = fp16(2P), SS[c] = sum_d meanh*P. 64 blocks x 512 thr.
extern "C" __global__ __launch_bounds__(512, 2)
void mel_prep(const float* __restrict__ MEAN, const unsigned short* __restrict__ SYT,
              unsigned short* __restrict__ GH, float* __restrict__ SS) {
  extern __shared__ __align__(16) char lds[];
  const int t = threadIdx.x, lane = t & 63, w = t >> 6;
  const int l = blockIdx.x & 3, ct = blockIdx.x >> 2;
  const int row0 = ct * 64;
  const int col0 = w * 64, lrow = lane & 15, lkg = lane >> 4;
  const int lke = lkg << 3;

  {  // stage 64 mean rows as fp16 (rows >= CDIM -> 0); [64][512] XOR-granule layout
    const int srow = t >> 3;
    const int grow = row0 + srow;
    const float* mr = MEAN + ((size_t)l * CDIM + grow) * DDIM + ((t & 7) << 3);
    const int swb = srow * 1024 + (((t & 7) ^ (srow & 7)) << 4);
    const float4 z4 = {0.f, 0.f, 0.f, 0.f};
    for (int c = 0; c < 8; ++c) {
      float4 x = z4, y = z4;
      if (grow < CDIM) { x = *(const float4*)(mr + c * 64); y = *(const float4*)(mr + c * 64 + 4); }
      *(f16x8*)(lds + swb + c * 128) = cvt8(x, y);
    }
  }
  __syncthreads();

  f32x4 acc[4][4];
#pragma unroll
  for (int i = 0; i < 4; ++i)
#pragma unroll
    for (int j = 0; j < 4; ++j) acc[i][j] = {0.f, 0.f, 0.f, 0.f};

  for (int c = 0; c < 8; ++c) {
#pragma unroll
    for (int ks = 0; ks < 2; ++ks) {
      const int k = c * 64 + ks * 32 + lke;
      f16x8 b0 = *(const f16x8*)(SYT + syt_off(l, col0 + lrow, k));
      f16x8 b1 = *(const f16x8*)(SYT + syt_off(l, col0 + 16 + lrow, k));
      f16x8 b2 = *(const f16x8*)(SYT + syt_off(l, col0 + 32 + lrow, k));
      f16x8 b3 = *(const f16x8*)(SYT + syt_off(l, col0 + 48 + lrow, k));
      const int xo = c * 128 + ((((ks << 2) + lkg) ^ (lrow & 7)) << 4);
      f16x8 a0 = *(const f16x8*)(lds + lrow * 1024 + xo);
      f16x8 a1 = *(const f16x8*)(lds + (16 + lrow) * 1024 + xo);
      f16x8 a2 = *(const f16x8*)(lds + (32 + lrow) * 1024 + xo);
      f16x8 a3 = *(const f16x8*)(lds + (48 + lrow) * 1024 + xo);
#pragma unroll
      for (int nf = 0; nf < 4; ++nf) {
        f16x8 a = nf == 0 ? a0 : nf == 1 ? a1 : nf == 2 ? a2 : a3;
        acc[nf][0] = __builtin_amdgcn_mfma_f32_16x16x32_f16(a, b0, acc[nf][0], 0, 0, 0);
        acc[nf][1] = __builtin_amdgcn_mfma_f32_16x16x32_f16(a, b1, acc[nf][1], 0, 0, 0);
        acc[nf][2] = __builtin_amdgcn_mfma_f32_16x16x32_f16(a, b2, acc[nf][2], 0, 0, 0);
        acc[nf][3] = __builtin_amdgcn_mfma_f32_16x16x32_f16(a, b3, acc[nf][3], 0, 0, 0);
      }
    }
  }

#pragma unroll
  for (int nf = 0; nf < 4; ++nf)
#pragma unroll
    for (int r = 0; r < 4; ++r) {
      const int nloc = nf * 16 + lkg * 4 + r;
      const int grow = row0 + nloc;
      float sp = 0.f;
#pragma unroll
      for (int df = 0; df < 4; ++df) {
        const int dcol = col0 + df * 16 + lrow;
        const float av = acc[nf][df][r];  // P[c,d]
        const float mh = h2f(*(const unsigned short*)(
            lds + nloc * 1024 + (((dcol >> 3) ^ (nloc & 7)) << 4) + (dcol & 7) * 2));
        sp += mh * av;
        if (grow < CDIM) GH[((size_t)l * CDIM + grow) * DDIM + dcol] = f2h(2.f * av);
      }
      sp += __shfl_xor(sp, 1); sp += __shfl_xor(sp, 2);
      sp += __shfl_xor(sp, 4); sp += __shfl_xor(sp, 8);
      if (lrow == 0 && grow < CDIM) atomicAdd(SS + l * 1024 + grow, sp);
    }
}

// K2 main: quarter-pipelined A staging + barrier-light K-loop; B direct from SYT (L2);
// epilogue fh from the LDS A-image. 512 thr / 8 waves; 2 blocks/CU.
extern "C" __global__ __launch_bounds__(512, 4)
void mel_main(const float* __restrict__ F, const float* __restrict__ W,
              const int* __restrict__ IDX, const unsigned short* __restrict__ SYT,
              const unsigned short* __restrict__ GH, const float* __restrict__ SS,
              float* __restrict__ OUT) {
  extern __shared__ __align__(16) char lds[];
  int* ids = (int*)(lds + IDS_OFF);
  float* sval = (float*)(lds + SVAL_OFF);
  float* red = (float*)(lds + RED_OFF);
  const int t = threadIdx.x, lane = t & 63, w = t >> 6;  // 8 waves
  const int bid = blockIdx.x, xcd = bid & 7, l = xcd >> 1;
  const int bx = ((bid >> 3) << 1) | (xcd & 1);  // 0..255 within l
  const int n0 = bx * 64;
  const int col0 = w * 64;                        // wave's 64 cols
  const int lrow = lane & 15, lkg = lane >> 4;

  if (t < 64) {
    const int cc = IDX[n0 + t];
    ids[t] = cc;
    sval[t] = SS[l * 1024 + cc];
  }

  // A staging coords: row t>>3, e-quad (t&7)*4 within each 32-wide chunk
  const int a_row = t >> 3, a_el = (t & 7) << 2;
  const float* fA = F + ((size_t)l * NDIM + n0 + a_row) * DDIM + a_el;
  const int a_wb = a_row * 64 + ((((a_el >> 3) + ((a_row >> 1) & 3)) & 3) << 4) +
                   ((a_el & 7) << 1);

  {  // prologue: quarter 0 (chunks 0-3)
    float4 x0 = *(const float4*)(fA);
    float4 x1 = *(const float4*)(fA + 32);
    float4 x2 = *(const float4*)(fA + 64);
    float4 x3 = *(const float4*)(fA + 96);
    *(ushort4*)(lds + 0 * 4096 + a_wb) = make_ushort4(f2h(x0.x), f2h(x0.y), f2h(x0.z), f2h(x0.w));
    *(ushort4*)(lds + 1 * 4096 + a_wb) = make_ushort4(f2h(x1.x), f2h(x1.y), f2h(x1.z), f2h(x1.w));
    *(ushort4*)(lds + 2 * 4096 + a_wb) = make_ushort4(f2h(x2.x), f2h(x2.y), f2h(x2.z), f2h(x2.w));
    *(ushort4*)(lds + 3 * 4096 + a_wb) = make_ushort4(f2h(x3.x), f2h(x3.y), f2h(x3.z), f2h(x3.w));
  }
  __syncthreads();

  f32x4 acc[4][4];  // [nf rows][df cols]
#pragma unroll
  for (int i = 0; i < 4; ++i)
#pragma unroll
    for (int j = 0; j < 4; ++j) acc[i][j] = {0.f, 0.f, 0.f, 0.f};

  // ---- quarter-pipelined K-loop: load quarter q+1 early, compute quarter q,
  //      write quarter q+1 after, barrier. B straight from SYT (L2).
#pragma unroll
  for (int q = 0; q < 4; ++q) {
    float4 n0v, n1v, n2v, n3v;
    if (q < 3) {  // issue next quarter's F loads (consumed after compute)
      const float* fn = fA + (q + 1) * 128;
      n0v = *(const float4*)(fn);
      n1v = *(const float4*)(fn + 32);
      n2v = *(const float4*)(fn + 64);
      n3v = *(const float4*)(fn + 96);
    }
#pragma unroll
    for (int s4 = 0; s4 < 4; ++s4) {
      const int s = q * 4 + s4;
      f16x8 bf[4], af[4];
#pragma unroll
      for (int df = 0; df < 4; ++df)
        bf[df] = *(const f16x8*)(SYT + syt_off(l, col0 + df * 16 + lrow, s * 32 + lkg * 8));
#pragma unroll
      for (int nf = 0; nf < 4; ++nf) {
        const int row = nf * 16 + lrow;
        af[nf] = *(const f16x8*)(lds + s * 4096 + row * 64 +
                                 (((lkg + ((row >> 1) & 3)) & 3) << 4));
      }
#pragma unroll
      for (int nf = 0; nf < 4; ++nf)
#pragma unroll
        for (int df = 0; df < 4; ++df)
          acc[nf][df] = __builtin_amdgcn_mfma_f32_16x16x32_f16(af[nf], bf[df], acc[nf][df], 0, 0, 0);
    }
    if (q < 3) {
      char* base = lds + (q + 1) * 16384;
      *(ushort4*)(base + 0 * 4096 + a_wb) = make_ushort4(f2h(n0v.x), f2h(n0v.y), f2h(n0v.z), f2h(n0v.w));
      *(ushort4*)(base + 1 * 4096 + a_wb) = make_ushort4(f2h(n1v.x), f2h(n1v.y), f2h(n1v.z), f2h(n1v.w));
      *(ushort4*)(base + 2 * 4096 + a_wb) = make_ushort4(f2h(n2v.x), f2h(n2v.y), f2h(n2v.z), f2h(n2v.w));
      *(ushort4*)(base + 3 * 4096 + a_wb) = make_ushort4(f2h(n3v.x), f2h(n3v.y), f2h(n3v.z), f2h(n3v.w));
      __syncthreads();
    }
  }

  // ---- epilogue: q-partial = sum_d fh*(W[n,d] - GH[c,d]); fh from LDS A-image.
  const unsigned short* gh_l = GH + (size_t)l * CDIM * DDIM;
  float tsum = 0.f;
#pragma unroll
  for (int nf = 0; nf < 4; ++nf)
#pragma unroll
    for (int df = 0; df < 4; ++df) {
      const int col = col0 + df * 16 + lrow;
      f32x4 cfrag = acc[nf][df];
#pragma unroll
      for (int r = 0; r < 4; ++r) {
        const int rowl = nf * 16 + lkg * 4 + r;
        const float fh = h2f(*(const unsigned short*)(
            lds + (col >> 5) * 4096 + rowl * 64 +
            (((((col & 31) >> 3) + ((rowl >> 1) & 3)) & 3) << 4) + ((col & 7) << 1)));
        const float gh = h2f(gh_l[(size_t)ids[rowl] * DDIM + col]);
        tsum += fh * (cfrag[r] - gh);
        if (w == 0 && df == 0 && lrow == 0) tsum += sval[rowl];
      }
    }
#pragma unroll
  for (int off = 32; off > 0; off >>= 1) tsum += __shfl_down(tsum, off);
  __syncthreads();
  if (lane == 0) red[w] = tsum;
  __syncthreads();
  if (t == 0) {
    float ssum = 0.f;
#pragma unroll
    for (int i = 0; i < 8; ++i) ssum += red[i];
    atomicAdd(OUT, ssum * (W[l] / (float)NDIM));
  }
}

// Correct-but-slow fp32 fallback (only if ws_size < WS_NEED).
extern "C" __global__ void mel_fallback(const float* __restrict__ F,
                                        const float* __restrict__ MEAN,
                                        const float* __restrict__ IC,
                                        const float* __restrict__ W,
                                        const int* __restrict__ IDX,
                                        float* __restrict__ OUT) {
  __shared__ float v[8][DDIM];
  __shared__ float red[256];
  const int t = threadIdx.x;
  const int l = blockIdx.y;
  const int n0 = blockIdx.x * 8;
  for (int i = t; i < 8 * DDIM; i += 256) {
    int n = i >> 9, e = i & 511;
    int c = IDX[n0 + n];
    v[n][e] = F[((size_t)l * NDIM + n0 + n) * DDIM + e] -
              MEAN[((size_t)l * CDIM + c) * DDIM + e];
  }
  __syncthreads();
  const float* icl = IC + ((size_t)l << 18);
  float part = 0.f;
  for (int rep = 0; rep < 2; ++rep) {
    int d = t + rep * 256;
    float s[8];
#pragma unroll
    for (int j = 0; j < 8; ++j) s[j] = 0.f;
    for (int e = 0; e < DDIM; ++e) {
      float m = icl[(size_t)d * DDIM + e];
#pragma unroll
      for (int j = 0; j < 8; ++j) s[j] += m * v[j][e];
    }
#pragma unroll
    for (int j = 0; j < 8; ++j) part += v[j][d] * s[j];
  }
  red[t] = part;
  __syncthreads();
  for (int o = 128; o > 0; o >>= 1) {
    if (t < o) red[t] += red[t + o];
    __syncthreads();
  }
  if (t == 0) atomicAdd(OUT, red[0] * (W[l] / (float)NDIM));
}

extern "C" void kernel_launch(void* const* d_in, const int* in_sizes, int n_in,
                              void* d_out, int out_size, void* d_ws, size_t ws_size,
                              hipStream_t stream) {
  const float* F = (const float*)d_in[0];
  const float* MEAN = (const float*)d_in[1];
  const float* IC = (const float*)d_in[2];
  const float* W = (const float*)d_in[3];
  const int* IDX = (const int*)d_in[4];
  float* OUT = (float*)d_out;

  hipMemsetAsync(d_out, 0, sizeof(float) * (size_t)out_size, stream);

  if (ws_size >= WS_NEED) {
    unsigned short* SYTp = (unsigned short*)d_ws;
    unsigned short* GHp = (unsigned short*)((char*)d_ws + GH_OFF);
    float* SSp = (float*)((char*)d_ws + SS_OFF);
    hipMemsetAsync(SSp, 0, SS_FLOATS * 4, stream);
    mel_mconv<<<dim3(1024), dim3(256), 0, stream>>>(IC, SYTp);
    (void)hipFuncSetAttribute(reinterpret_cast<const void*>(mel_prep),
                              hipFuncAttributeMaxDynamicSharedMemorySize, LDS_PREP);
    mel_prep<<<dim3(64), dim3(512), LDS_PREP, stream>>>(MEAN, SYTp, GHp, SSp);
    (void)hipFuncSetAttribute(reinterpret_cast<const void*>(mel_main),
                              hipFuncAttributeMaxDynamicSharedMemorySize, LDS_MAIN);
    mel_main<<<dim3(1024), dim3(512), LDS_MAIN, stream>>>(
        F, W, IDX, SYTp, GHp, SSp, OUT);
  } else {
    mel_fallback<<<dim3(NDIM / 8, LDIM), dim3(256), 0, stream>>>(F, MEAN, IC, W, IDX, OUT);
  }
}